// Round 5
// baseline (127.593 us; speedup 1.0000x reference)
//
#include <hip/hip_runtime.h>

// Xonv2D: per-location conv. B=32, CIN=16, H=W=64, COUT=32, K=3, pad=1.
// out[b,o,h,w] = sum_{c,kh,kw} x[b,c,h+kh-1,w+kw-1] * W[h,w,o,c,kh,kw] + bias[h,w,o]
//
// R5: 8 waves/block = 8 w-locations, grid 512 -> 2 blocks/CU (overlap).
// Weights staged per-wave through a private LDS double-buffer with coalesced
// full-line loads -> NO barriers in the K-loop (all deps intra-wave).
// h-octet XCD swizzle (XCD = h>>3) so adjacent h share x rows in XCD L2.
// x windows: 4 aligned float4/row, dword-aligned bf16 LDS writes, gather
// stride 674 hw (bank stride 17, odd) -> conflict-free.

#define HW_ 4096
#define PP  144
#define RST 14     // hw per (b, c*3+r) row; slot = col - w0 + 4, gather uses 3..12
#define BST 674    // hw per b = 48*14 + 2 pad; byte-stride/4 = 337 == 17 mod 32

typedef float v4f  __attribute__((ext_vector_type(4)));
typedef float v16f __attribute__((ext_vector_type(16)));
typedef short v8s  __attribute__((ext_vector_type(8)));

__device__ __forceinline__ unsigned short f2bf(float f) {
    unsigned int u = __builtin_bit_cast(unsigned int, f);
    u += 0x7fffu + ((u >> 16) & 1u);          // RNE
    return (unsigned short)(u >> 16);
}
__device__ __forceinline__ unsigned int pk2(float a, float b) {
    return (unsigned int)f2bf(a) | ((unsigned int)f2bf(b) << 16);
}
__device__ __forceinline__ constexpr int offp(int p) {
    // p = c*9 + r*3 + kw -> hw offset within a b-row (add b*BST + wv at runtime)
    const int c = p / 9, rem = p % 9, r = rem / 3, kw = rem % 3;
    return (c * 3 + r) * RST + kw + 3;
}

__global__ __launch_bounds__(512, 4) void xonv_kernel(
    const float* __restrict__ x,
    const float* __restrict__ wt,
    const float* __restrict__ bias,
    float* __restrict__ out)
{
    const int t  = threadIdx.x;
    const int bi = blockIdx.x;                 // 0..511
    // XCD = bi&7 owns h in [8*xcd, 8*xcd+8), all 8 w-groups (x reuse in L2).
    const int xcd  = bi & 7;
    const int rem  = bi >> 3;
    const int hsub = rem & 7;
    const int wg   = rem >> 3;                 // 0..7
    const int h    = xcd * 8 + hsub;
    const int w0   = wg * 8;

    __shared__ alignas(16) unsigned short xs[21568];   // [32][BST] bf16 windows
    __shared__ alignas(16) unsigned short wb[8192];    // [8 wv][2 buf][512] bf16
    float* ol = (float*)xs;                            // epilogue alias

    const int l  = t & 63;
    const int wv = t >> 6;                     // wave = w-location 0..7
    const int o  = l & 31;                     // out-channel / batch lane idx
    const int kh = l >> 5;
    const int w  = w0 + wv;

    // ---- per-wave coalesced weight slice pointers (lane -> o-line, 16B seg) ----
    const int o2  = (l >> 2) & 15;
    const int seg = l & 3;
    const float* wbase = wt + (size_t)((h * 64 + w) * 32) * PP;
    const float* wp0 = wbase + (size_t)o2 * PP + seg * 4;
    const float* wp1 = wbase + (size_t)(o2 + 16) * PP + seg * 4;

    float4 c0a = *(const float4*)(wp0);          // slice 0
    float4 c0b = *(const float4*)(wp1);
    float4 cua = *(const float4*)(wp0 + 16);     // slice 1 (pending)
    float4 cub = *(const float4*)(wp1 + 16);

    const float bia = bias[(size_t)(h * 64 + w) * 32 + o];

    // ---------------- stage x: 1536 rows x 4 float4 windows ----------------
    // job j = t + 512*i: rid = j>>2 (row = b*48 + c*3 + r), sub = j&3.
    {
        const int sub  = t & 3;
        const int col4 = w0 - 4 + sub * 4;
        const bool colok = (col4 >= 0) && (col4 <= 60);
        const int rid0 = t >> 2;               // 0..127
        int b  = (rid0 * 683) >> 15;           // rid0/48
        int cr = rid0 - b * 48;
#pragma unroll
        for (int i = 0; i < 12; ++i) {
            const int c   = (cr * 43) >> 7;    // cr/3
            const int r   = cr - c * 3;
            const int row = h + r - 1;
            float4 f = {0.f, 0.f, 0.f, 0.f};
            if (colok && (unsigned)row < 64u)
                f = *(const float4*)(x + ((size_t)(b * 16 + c)) * HW_
                                       + row * 64 + col4);
            unsigned int* d = (unsigned int*)(xs + b * BST + cr * RST + sub * 4);
            d[0] = pk2(f.x, f.y);
            d[1] = pk2(f.z, f.w);
            b += 2; cr += 32; if (cr >= 48) { cr -= 48; ++b; }
        }
    }

    // ---- cvt slice 0 into this wave's LDS buf 0 (intra-wave only) ----
    const int wW = wv * 1024;
    {
        unsigned int* d0 = (unsigned int*)(wb + wW + o2 * 16 + seg * 4);
        d0[0] = pk2(c0a.x, c0a.y); d0[1] = pk2(c0a.z, c0a.w);
        unsigned int* d1 = (unsigned int*)(wb + wW + (o2 + 16) * 16 + seg * 4);
        d1[0] = pk2(c0b.x, c0b.y); d1[1] = pk2(c0b.z, c0b.w);
    }
    __syncthreads();   // x windows ready (weights need no barrier: intra-wave)

    // ---------------- K-loop: 9 x 32x32x16 MFMA, barrier-free ----------------
    const int gb  = o * BST + wv;              // A-gather base (batch = o lane)
    const int bfr = wW + o * 16 + kh * 8;      // B-frag hw offset (+ buf*512)

    v16f acc;
#pragma unroll
    for (int i = 0; i < 16; ++i) acc[i] = 0.f;

#pragma unroll
    for (int kc = 0; kc < 9; ++kc) {
        v8s bf = *(const v8s*)(wb + (kc & 1) * 512 + bfr);

        v8s a;
#pragma unroll
        for (int j = 0; j < 8; ++j) {
            const int C0 = offp(kc * 16 + j);
            const int C1 = offp(kc * 16 + 8 + j);
            a[j] = (short)xs[gb + (kh ? C1 : C0)];
        }

        if (kc < 8) {   // cvt pending slice -> other buf; issue slice kc+2
            const int nb = wW + ((kc + 1) & 1) * 512;
            unsigned int* d0 = (unsigned int*)(wb + nb + o2 * 16 + seg * 4);
            d0[0] = pk2(cua.x, cua.y); d0[1] = pk2(cua.z, cua.w);
            unsigned int* d1 = (unsigned int*)(wb + nb + (o2 + 16) * 16 + seg * 4);
            d1[0] = pk2(cub.x, cub.y); d1[1] = pk2(cub.z, cub.w);
            if (kc < 7) {
                cua = *(const float4*)(wp0 + (kc + 2) * 16);
                cub = *(const float4*)(wp1 + (kc + 2) * 16);
            }
        }

        acc = __builtin_amdgcn_mfma_f32_32x32x16_bf16(a, bf, acc, 0, 0, 0);
    }

    // ---------------- epilogue: bias + LDS transpose + coalesced stores ----
    __syncthreads();   // all xs gathers done; reuse xs as ol[1024][9]

#pragma unroll
    for (int r = 0; r < 16; ++r) {
        const int brow = (r & 3) + 8 * (r >> 2) + 4 * kh;   // batch 0..31
        ol[(brow * 32 + o) * 9 + wv] = acc[r] + bia;
    }
    __syncthreads();

#pragma unroll
    for (int i2 = 0; i2 < 4; ++i2) {
        const int flat = t + i2 * 512;
        const int bo   = flat >> 1;            // b*32 + o, 0..1023
        const int q4   = flat & 1;
        const int base = bo * 9 + q4 * 4;
        float4 v;
        v.x = ol[base + 0]; v.y = ol[base + 1];
        v.z = ol[base + 2]; v.w = ol[base + 3];
        *(float4*)(out + (size_t)bo * HW_ + h * 64 + w0 + q4 * 4) = v;
    }
}

extern "C" void kernel_launch(void* const* d_in, const int* in_sizes, int n_in,
                              void* d_out, int out_size, void* d_ws, size_t ws_size,
                              hipStream_t stream) {
    const float* x       = (const float*)d_in[0];
    const float* weights = (const float*)d_in[1];
    const float* bias    = (const float*)d_in[2];
    float* out           = (float*)d_out;
    (void)in_sizes; (void)n_in; (void)out_size; (void)d_ws; (void)ws_size;

    dim3 grid(512);    // 64 h x 8 w-groups, h-octet XCD swizzle; 2 blocks/CU
    dim3 block(512);   // 8 waves = 8 w-locations
    hipLaunchKernelGGL(xonv_kernel, grid, block, 0, stream, x, weights, bias, out);
}

// Round 6
// 124.132 us; speedup vs baseline: 1.0279x; 1.0279x over previous
//
#include <hip/hip_runtime.h>

// Xonv2D: per-location conv. B=32, CIN=16, H=W=64, COUT=32, K=3, pad=1.
// out[b,o,h,w] = sum_{c,kh,kw} x[b,c,h+kh-1,w+kw-1] * W[h,w,o,c,kh,kw] + bias[h,w,o]
//
// R6 = R4 (best: 36.5us kernel) + depth-4 rotating weight prefetch.
// Theory: R4's depth-2 slice pipeline (2KB/wave in flight) cannot cover the
// ~900-cycle HBM latency at ~120-cycle iterations, capping outstanding reads.
// Depth-4 doubles per-wave read concurrency; everything else unchanged so the
// delta is attributable. If neutral -> read-path concurrency ceiling
// (~2.8 TB/s, MSHR-limited) is confirmed and we are at the practical roofline.

#define CIN  16
#define HW_  4096            // H*W
#define PP   144             // CIN*3*3
#define RST  20              // hw per (b, c*3+r) row: slot = col - w0 + 2
#define BST  962             // hw per b: 48*20 + 2 pad (dw stride 481 == 1 mod 32)

typedef float v4f  __attribute__((ext_vector_type(4)));
typedef float v16f __attribute__((ext_vector_type(16)));
typedef short v8s  __attribute__((ext_vector_type(8)));

__device__ __forceinline__ unsigned short f2bf(float f) {
    unsigned int u = __builtin_bit_cast(unsigned int, f);
    u += 0x7fffu + ((u >> 16) & 1u);          // RNE
    return (unsigned short)(u >> 16);
}
__device__ __forceinline__ unsigned int pk2(float a, float b) {
    return (unsigned int)f2bf(a) | ((unsigned int)f2bf(b) << 16);
}
__device__ __forceinline__ constexpr int offp(int p) {
    // p = c*9 + r*3 + kw  ->  LDS hw offset (row part + kw + 1)
    const int c = p / 9, rem = p % 9, r = rem / 3, kw = rem % 3;
    return (c * 3 + r) * RST + kw + 1;
}

__global__ __launch_bounds__(1024, 4) void xonv_kernel(
    const float* __restrict__ x,
    const float* __restrict__ wt,
    const float* __restrict__ bias,
    float* __restrict__ out)
{
    const int t  = threadIdx.x;
    const int bi = blockIdx.x;                 // 0..255
    // XCD swizzle: bi&7 = h&7 -> all 4 w-groups of a row on one XCD.
    const int h  = ((bi >> 5) << 3) + (bi & 7);
    const int wg = (bi >> 3) & 3;
    const int w0 = wg << 4;

    __shared__ unsigned short xs[32 * BST];    // 61,568 B
    float* ol = (float*)xs;                    // epilogue alias (34,816 B)

    const int l  = t & 63;
    const int wv = t >> 6;                     // wave = location 0..15
    const int w  = w0 + wv;
    const int o  = l & 31;                     // out-channel col / batch lane idx
    const int kh = l >> 5;                     // k-half (0/1)

    // ---- weight slice pointers; depth-4 rotating prefetch issued EARLY ----
    const float* wp = wt + (size_t)(h * 64 + w) * (32 * PP)
                         + (size_t)o * PP + kh * 8;
    float4 ca[4], cb[4];
#pragma unroll
    for (int s = 0; s < 4; ++s) {
        ca[s] = *(const float4*)(wp + s * 16);
        cb[s] = *(const float4*)(wp + s * 16 + 4);
    }
    const float bia = bias[(size_t)(h * 64 + w) * 32 + o];

    // ---------------- stage x windows: 1536 rows x 6 float4 ----------------
    // job j: rid = j/6 (row = b*48 + c*3 + r), sub = j%6; window col w0-4+sub*4
    const int wstart = w0 - 4;
#pragma unroll
    for (int i = 0; i < 9; ++i) {
        const int j   = t + i * 1024;
        const int rid = (int)(((unsigned)j * 43691u) >> 18);   // j/6
        const int sub = j - rid * 6;
        const int b   = (rid * 683) >> 15;                     // rid/48
        const int cr  = rid - b * 48;
        const int c   = (cr * 43) >> 7;                        // cr/3
        const int r   = cr - c * 3;
        const int row = h + r - 1;
        const int col4 = wstart + sub * 4;
        float4 f = {0.f, 0.f, 0.f, 0.f};
        if ((unsigned)row < 64u && (unsigned)col4 <= 60u)
            f = *(const float4*)(x + ((size_t)(b * CIN + c)) * HW_
                                   + row * 64 + col4);
        unsigned short* dst = xs + b * BST + cr * RST;
        if (sub == 0) {
            ((unsigned int*)dst)[0] = pk2(f.z, f.w);           // slots 0,1
        } else if (sub == 5) {
            ((unsigned int*)dst)[9] = pk2(f.x, f.y);           // slots 18,19
        } else {
            unsigned int* d = (unsigned int*)(dst + sub * 4 - 2);
            d[0] = pk2(f.x, f.y);                              // slots 4s-2..
            d[1] = pk2(f.z, f.w);
        }
    }
    __syncthreads();

    // ---------------- compute: one wave per location, 9 x 32x32x16 ---------
    const int gb = o * BST + wv;               // per-lane gather base (hw)

    v16f acc;
#pragma unroll
    for (int i = 0; i < 16; ++i) acc[i] = 0.f;

#pragma unroll
    for (int kc = 0; kc < 9; ++kc) {
        const int slot = kc & 3;

        // pack B-frag from the slice loaded 4 iterations ago
        union { unsigned int u[4]; v8s s; } ub;
        ub.u[0] = pk2(ca[slot].x, ca[slot].y);
        ub.u[1] = pk2(ca[slot].z, ca[slot].w);
        ub.u[2] = pk2(cb[slot].x, cb[slot].y);
        ub.u[3] = pk2(cb[slot].z, cb[slot].w);

        // refill the slot with slice kc+4 (keeps 4 slices in flight)
        if (kc + 4 < 9) {
            ca[slot] = *(const float4*)(wp + (kc + 4) * 16);
            cb[slot] = *(const float4*)(wp + (kc + 4) * 16 + 4);
        }

        v8s a;
#pragma unroll
        for (int j = 0; j < 8; ++j) {
            const int C0 = offp(kc * 16 + j);        // compile-time
            const int C1 = offp(kc * 16 + 8 + j);    // compile-time
            a[j] = (short)xs[gb + (kh ? C1 : C0)];
        }

        acc = __builtin_amdgcn_mfma_f32_32x32x16_bf16(a, ub.s, acc, 0, 0, 0);
    }

    __syncthreads();   // all xs gathers done; reuse LDS as ol[512][17]

    // ---------------- epilogue: two b-halves, full-line stores -------------
#pragma unroll
    for (int half = 0; half < 2; ++half) {
#pragma unroll
        for (int rr = 0; rr < 8; ++rr) {
            const int r     = half * 8 + rr;
            const int browl = (r & 3) + 8 * ((r >> 2) & 1) + 4 * kh;  // 0..15
            ol[(browl * 32 + o) * 17 + wv] = acc[r] + bia;
        }
        __syncthreads();
#pragma unroll
        for (int i2 = 0; i2 < 2; ++i2) {
            const int flat = t + i2 * 1024;
            const int bol  = flat >> 2;            // 0..511 : browl*32+o
            const int q4   = flat & 3;
            const int base = bol * 17 + q4 * 4;
            float4 v;
            v.x = ol[base + 0]; v.y = ol[base + 1];
            v.z = ol[base + 2]; v.w = ol[base + 3];
            const int bg = half * 16 + (bol >> 5);         // batch
            const int og = bol & 31;                       // out-channel
            *(float4*)(out + ((size_t)(bg * 32 + og)) * HW_
                           + h * 64 + w0 + q4 * 4) = v;
        }
        __syncthreads();
    }
}

extern "C" void kernel_launch(void* const* d_in, const int* in_sizes, int n_in,
                              void* d_out, int out_size, void* d_ws, size_t ws_size,
                              hipStream_t stream) {
    const float* x       = (const float*)d_in[0];
    const float* weights = (const float*)d_in[1];
    const float* bias    = (const float*)d_in[2];
    float* out           = (float*)d_out;
    (void)in_sizes; (void)n_in; (void)out_size; (void)d_ws; (void)ws_size;

    dim3 grid(256);     // 64 h x 4 w-groups, XCD-swizzled
    dim3 block(1024);   // 16 waves = 16 w-locations
    hipLaunchKernelGGL(xonv_kernel, grid, block, 0, stream, x, weights, bias, out);
}